// Round 13
// baseline (188.554 us; speedup 1.0000x reference)
//
#include <hip/hip_runtime.h>
#include <math.h>

// Problem constants
#define NB 2
#define NC 19      // classes
#define NH 128
#define NW 128
#define NCF 64     // feature channels
#define NHE 64     // ema logits H/W
#define NHX 32     // x_ema H/W
#define EPSC 1e-8f

// d_ws: acc[0]=sum(lp), acc[1]=sum(ln), acc[2]=mask count; cn at +64B (2048 f32)
__global__ void pfst_init(float* __restrict__ acc) {
    acc[0] = 0.f; acc[1] = 0.f; acc[2] = 0.f;
}

// Cell norms: cn[b*1024+pos] = sum_c xe[b,c,pos]^2  (center- independent,
// hoisted out of the main kernel; halves phase-1 work and registers)
__global__ __launch_bounds__(256) void pfst_norm(const float* __restrict__ xe,
                                                 float* __restrict__ cn) {
    int idx = blockIdx.x * 256 + threadIdx.x;    // < 2048
    int b = idx >> 10, pos = idx & 1023;
    const float* X = xe + b * (NCF * 1024) + pos;
    float s = 0.f;
    #pragma unroll
    for (int c = 0; c < NCF; c++) { float v = X[c * 1024]; s = fmaf(v, v, s); }
    cn[idx] = s;
}

// Gather for this lane's 1-2 classes: accumulate val * bilinear(ema)[tap k].
__device__ __forceinline__ void gather2(const float* __restrict__ Lc0,
                                        const float* __restrict__ Lc1, bool two,
                                        int k, float val, int h, int w,
                                        float& a0, float& a1) {
    int i = (k * 586) >> 12;          // k/7 for k<64
    int j = k - 7 * i;
    int py = h + 2 * i - 6, px = w + 2 * j - 6;
    if ((unsigned)py < 128u && (unsigned)px < 128u) {
        int iy0 = (py - 1) >> 1; float ty = (py & 1) ? 0.25f : 0.75f;
        int ix0 = (px - 1) >> 1; float tx = (px & 1) ? 0.25f : 0.75f;
        int y0 = iy0 < 0 ? 0 : iy0;
        int y1 = (iy0 + 1) > 63 ? 63 : (iy0 + 1);
        int x0 = ix0 < 0 ? 0 : ix0;
        int x1 = (ix0 + 1) > 63 ? 63 : (ix0 + 1);
        float w00 = (1.f - ty) * (1.f - tx), w01 = (1.f - ty) * tx;
        float w10 = ty * (1.f - tx),         w11 = ty * tx;
        int o00 = y0 * 64 + x0, o01 = y0 * 64 + x1;
        int o10 = y1 * 64 + x0, o11 = y1 * 64 + x1;
        float g0 = w00 * Lc0[o00] + w01 * Lc0[o01] + w10 * Lc0[o10] + w11 * Lc0[o11];
        a0 = fmaf(val, g0, a0);
        if (two) {
            float g1 = w00 * Lc1[o00] + w01 * Lc1[o01] + w10 * Lc1[o10] + w11 * Lc1[o11];
            a1 = fmaf(val, g1, a1);
        }
    }
}

// 16 lanes per pixel. Lane l: 4 feature channels (phase 1), taps {l+16m}
// (selection), classes {l, l+16 if l<3} (gather + softmax/BCE).
__global__ __launch_bounds__(256, 8) void pfst_main(
    const float* __restrict__ trg, const float* __restrict__ ema,
    const float* __restrict__ xe,  const float* __restrict__ mix,
    const float* __restrict__ cn,  float* __restrict__ acc)
{
    int tid = threadIdx.x;
    int l = tid & 15;                 // lane in group
    int g = tid >> 4;                 // pixel slot in block (0..15)
    int p = blockIdx.x * 16 + g;      // < 32768
    int b = p >> 14; int rem = p & 16383;
    int h = rem >> 7; int w = rem & 127;

    float mval = mix[(b << 14) + rem];
    bool active = mval < 0.5f;        // (1 - mix) > 0.5

    // ---------- Phase 1: dotc partials (4 channels/lane), cell offsets ----------
    const float* Xb = xe + b * (NCF * NHX * NHX);
    const float* CNb = cn + (b << 10);
    int yc = h >> 2, xc = w >> 2;
    int by = (h - 6) >> 2, bx = (w - 6) >> 2;

    int offs[16];
    #pragma unroll
    for (int a = 0; a < 4; a++) {
        int cy = by + a; cy = cy < 0 ? 0 : (cy > 31 ? 31 : cy);
        #pragma unroll
        for (int d = 0; d < 4; d++) {
            int cx2 = bx + d; cx2 = cx2 < 0 ? 0 : (cx2 > 31 ? 31 : cx2);
            offs[a * 4 + d] = cy * 32 + cx2;
        }
    }
    int coff = yc * 32 + xc;

    float dotc[16];
    #pragma unroll
    for (int e = 0; e < 16; e++) dotc[e] = 0.f;

    const float* Xl = Xb + (l << 2) * (NHX * NHX);   // this lane's 4 channels
    #pragma unroll
    for (int cc = 0; cc < 4; cc++) {
        const float* Xc = Xl + cc * (NHX * NHX);
        float cv = Xc[coff];
        #pragma unroll
        for (int e = 0; e < 16; e++) dotc[e] = fmaf(Xc[offs[e]], cv, dotc[e]);
    }

    // Reduce-scatter across 16 lanes: lane l ends with total for cell l.
    // Step mask m: keep lower half if (l&m)==0; verified lane->element == l.
    float c8[8];
    {
        bool hi = (l & 8);
        #pragma unroll
        for (int q = 0; q < 8; q++) {
            float sv = hi ? dotc[q] : dotc[q + 8];
            float rv = __shfl_xor(sv, 8);
            c8[q] = (hi ? dotc[q + 8] : dotc[q]) + rv;
        }
    }
    float c4[4];
    {
        bool hi = (l & 4);
        #pragma unroll
        for (int q = 0; q < 4; q++) {
            float sv = hi ? c4[0] : c4[0]; // placeholder avoided below
            sv = hi ? c8[q] : c8[q + 4];
            float rv = __shfl_xor(sv, 4);
            c4[q] = (hi ? c8[q + 4] : c8[q]) + rv;
        }
    }
    float c2[2];
    {
        bool hi = (l & 2);
        #pragma unroll
        for (int q = 0; q < 2; q++) {
            float sv = hi ? c4[q] : c4[q + 2];
            float rv = __shfl_xor(sv, 2);
            c2[q] = (hi ? c4[q + 2] : c4[q]) + rv;
        }
    }
    float c1;
    {
        bool hi = (l & 1);
        float sv = hi ? c2[0] : c2[1];
        float rv = __shfl_xor(sv, 1);
        c1 = (hi ? c2[1] : c2[0]) + rv;
    }

    // This lane's cell coords (cell index e == l)
    float scell_l;
    {
        int a = l >> 2, d = l & 3;
        int cy = by + a; cy = cy < 0 ? 0 : (cy > 31 ? 31 : cy);
        int cx2 = bx + d; cx2 = cx2 < 0 ? 0 : (cx2 > 31 ? 31 : cx2);
        float nu = fmaxf(sqrtf(CNb[cy * 32 + cx2]), EPSC);
        float nc = fmaxf(sqrtf(CNb[coff]), EPSC);
        scell_l = c1 / (nu * nc);
    }

    __shared__ float sc[16][16];
    sc[g][l] = scell_l;
    __syncthreads();   // uniform (all code unconditional)

    // ---------- Phase 2: this lane's sims (taps k = l+16m) ----------
    bool ry = (h & 3) >= 2, rx = (w & 3) >= 2;
    float osim[4];
    unsigned unavail = 0u;
    #pragma unroll
    for (int m = 0; m < 4; m++) {
        int k = l + 16 * m;
        if (k < 49) {
            int i = (k * 586) >> 12; int j = k - 7 * i;
            int py = h + 2 * i - 6, px = w + 2 * j - 6;
            bool valid = (unsigned)py < 128u && (unsigned)px < 128u;
            int a = ry ? (i >> 1) : ((i + 1) >> 1);   // QA / QB patterns
            int d = rx ? (j >> 1) : ((j + 1) >> 1);
            float v = sc[g][a * 4 + d];
            osim[m] = valid ? v : 0.f;
        } else { osim[m] = 0.f; unavail |= 1u << m; }
    }

    // ---------- Phase 3+4: distributed top-9 / bottom-8 + gather ----------
    const float* Lb = ema + b * NC * NHE * NHE;
    bool two = (l < 3);
    const float* Lc0 = Lb + l * (NHE * NHE);
    const float* Lc1 = Lb + (l + 16) * (NHE * NHE);   // only read when two
    float ap0 = 0.f, ap1 = 0.f, an0 = 0.f, an1 = 0.f;

    // Pos: top-9 by value, ties -> lowest tap index (matches lax.top_k).
    {
        unsigned mask = unavail;
        #pragma unroll 1
        for (int t = 0; t < 9; t++) {
            float v = -3.4e38f; int idx = 63;
            #pragma unroll
            for (int m = 0; m < 4; m++) {
                if (!((mask >> m) & 1u) && osim[m] > v) { v = osim[m]; idx = l + 16 * m; }
            }
            #pragma unroll
            for (int s = 1; s < 16; s <<= 1) {
                float ov = __shfl_xor(v, s); int oi = __shfl_xor(idx, s);
                if (ov > v || (ov == v && oi < idx)) { v = ov; idx = oi; }
            }
            if ((idx & 15) == l) mask |= 1u << (idx >> 4);
            gather2(Lc0, Lc1, two, idx, v, h, w, ap0, ap1);
        }
    }
    // Neg: 8 smallest, ties -> lowest tap index (== top_k(-sim, 8)).
    {
        unsigned mask = unavail;
        #pragma unroll 1
        for (int t = 0; t < 8; t++) {
            float v = 3.4e38f; int idx = 63;
            #pragma unroll
            for (int m = 0; m < 4; m++) {
                if (!((mask >> m) & 1u) && osim[m] < v) { v = osim[m]; idx = l + 16 * m; }
            }
            #pragma unroll
            for (int s = 1; s < 16; s <<= 1) {
                float ov = __shfl_xor(v, s); int oi = __shfl_xor(idx, s);
                if (ov < v || (ov == v && oi < idx)) { v = ov; idx = oi; }
            }
            if ((idx & 15) == l) mask |= 1u << (idx >> 4);
            gather2(Lc0, Lc1, two, idx, v, h, w, an0, an1);
        }
    }

    // ---------- Phase 5: softmax + BCE, classes {l, l+16} ----------
    const float* Tb = trg + b * NC * (NH * NW) + (h << 7) + w;
    float x0 = Tb[l * (NH * NW)];
    float x1 = two ? Tb[(l + 16) * (NH * NW)] : 0.f;

    float mp = two ? fmaxf(ap0, ap1) : ap0;
    float mn = two ? fmaxf(an0, an1) : an0;
    #pragma unroll
    for (int s = 1; s < 16; s <<= 1) {
        mp = fmaxf(mp, __shfl_xor(mp, s));
        mn = fmaxf(mn, __shfl_xor(mn, s));
    }

    float ep = expf(ap0 - mp), en = expf(an0 - mn);
    float Zp = ep, Sp = ep * x0, Zn = en, Sn = en * x0;
    float ls = fminf(x0, 0.f) - log1pf(expf(-fabsf(x0)));
    float Bs = x0 - ls;
    if (two) {
        float ep1 = expf(ap1 - mp), en1 = expf(an1 - mn);
        Zp += ep1; Sp += ep1 * x1; Zn += en1; Sn += en1 * x1;
        float ls1 = fminf(x1, 0.f) - log1pf(expf(-fabsf(x1)));
        Bs += x1 - ls1;
    }
    #pragma unroll
    for (int s = 1; s < 16; s <<= 1) {
        Zp += __shfl_xor(Zp, s); Sp += __shfl_xor(Sp, s);
        Zn += __shfl_xor(Zn, s); Sn += __shfl_xor(Sn, s);
        Bs += __shfl_xor(Bs, s);
    }

    float lp = Bs - Sp / Zp;          // sum_c bce(x, pl_pos)
    float ln = Sn / Zn - Bs;          // sum_c -bce(x, pl_neg)
    if (!active || l != 0) { lp = 0.f; ln = 0.f; }
    float cm = (active && l == 0) ? 1.f : 0.f;

    // ---------- Wave reduce, block reduce, atomics ----------
    #pragma unroll
    for (int off = 32; off > 0; off >>= 1) {
        lp += __shfl_down(lp, off);
        ln += __shfl_down(ln, off);
        cm += __shfl_down(cm, off);
    }
    __shared__ float red[4][3];
    int wid = tid >> 6;
    if ((tid & 63) == 0) { red[wid][0] = lp; red[wid][1] = ln; red[wid][2] = cm; }
    __syncthreads();
    if (tid == 0) {
        atomicAdd(acc + 0, red[0][0] + red[1][0] + red[2][0] + red[3][0]);
        atomicAdd(acc + 1, red[0][1] + red[1][1] + red[2][1] + red[3][1]);
        atomicAdd(acc + 2, red[0][2] + red[1][2] + red[2][2] + red[3][2]);
    }
}

// Output: FLOAT32[2] = [loss_pos, 0.1*loss_neg] (decoded R0-R10, verified R11/R12).
__global__ void pfst_final(const float* __restrict__ acc, float* __restrict__ out) {
    float denom = acc[2] * (float)NC;
    out[0] = acc[0] / denom;              // loss_pos * W_POS(=1.0)
    out[1] = acc[1] / denom * 0.1f;       // loss_neg * W_NEG(=0.1)
}

extern "C" void kernel_launch(void* const* d_in, const int* in_sizes, int n_in,
                              void* d_out, int out_size, void* d_ws, size_t ws_size,
                              hipStream_t stream) {
    const float* trg = (const float*)d_in[0];   // [2,19,128,128]
    const float* ema = (const float*)d_in[1];   // [2,19,64,64]
    const float* xe  = (const float*)d_in[2];   // [2,64,32,32]
    const float* mix = (const float*)d_in[3];   // [2,1,128,128]
    float* acc = (float*)d_ws;
    float* cnw = (float*)((char*)d_ws + 64);    // 2048 floats
    float* out = (float*)d_out;

    hipLaunchKernelGGL(pfst_init, dim3(1), dim3(1), 0, stream, acc);
    hipLaunchKernelGGL(pfst_norm, dim3(8), dim3(256), 0, stream, xe, cnw);
    // 16 lanes/pixel: 16 pixels per 256-thread block -> 2048 blocks, 8192 waves.
    hipLaunchKernelGGL(pfst_main, dim3((NB * NH * NW) / 16), dim3(256), 0, stream,
                       trg, ema, xe, mix, cnw, acc);
    hipLaunchKernelGGL(pfst_final, dim3(1), dim3(1), 0, stream, acc, out);
}

// Round 14
// 144.764 us; speedup vs baseline: 1.3025x; 1.3025x over previous
//
#include <hip/hip_runtime.h>
#include <math.h>

// Problem constants
#define NB 2
#define NC 19      // classes
#define NH 128
#define NW 128
#define NCF 64     // feature channels
#define NHE 64     // ema logits H/W
#define NHX 32     // x_ema H/W
#define EPSC 1e-8f

// d_ws: acc[0]=sum(lp), acc[1]=sum(ln), acc[2]=mask count; cn at +64B (2048 f32)
__global__ void pfst_init(float* __restrict__ acc) {
    acc[0] = 0.f; acc[1] = 0.f; acc[2] = 0.f;
}

// Cell norms: cn[b*1024+pos] = sum_c xe[b,c,pos]^2 (hoisted, center-independent)
__global__ __launch_bounds__(256) void pfst_norm(const float* __restrict__ xe,
                                                 float* __restrict__ cn) {
    int idx = blockIdx.x * 256 + threadIdx.x;    // < 2048
    int b = idx >> 10, pos = idx & 1023;
    const float* X = xe + b * (NCF * 1024) + pos;
    float s = 0.f;
    #pragma unroll
    for (int c = 0; c < NCF; c++) { float v = X[c * 1024]; s = fmaf(v, v, s); }
    cn[idx] = s;
}

// Gather for this lane's 1-2 classes: accumulate val * bilinear(ema)[tap k].
__device__ __forceinline__ void gather2(const float* __restrict__ Lc0,
                                        const float* __restrict__ Lc1, bool two,
                                        int k, float val, int h, int w,
                                        float& a0, float& a1) {
    int i = (k * 586) >> 12;          // k/7 for k<64
    int j = k - 7 * i;
    int py = h + 2 * i - 6, px = w + 2 * j - 6;
    if ((unsigned)py < 128u && (unsigned)px < 128u) {
        int iy0 = (py - 1) >> 1; float ty = (py & 1) ? 0.25f : 0.75f;
        int ix0 = (px - 1) >> 1; float tx = (px & 1) ? 0.25f : 0.75f;
        int y0 = iy0 < 0 ? 0 : iy0;
        int y1 = (iy0 + 1) > 63 ? 63 : (iy0 + 1);
        int x0 = ix0 < 0 ? 0 : ix0;
        int x1 = (ix0 + 1) > 63 ? 63 : (ix0 + 1);
        float w00 = (1.f - ty) * (1.f - tx), w01 = (1.f - ty) * tx;
        float w10 = ty * (1.f - tx),         w11 = ty * tx;
        int o00 = y0 * 64 + x0, o01 = y0 * 64 + x1;
        int o10 = y1 * 64 + x0, o11 = y1 * 64 + x1;
        float g0 = w00 * Lc0[o00] + w01 * Lc0[o01] + w10 * Lc0[o10] + w11 * Lc0[o11];
        a0 = fmaf(val, g0, a0);
        if (two) {
            float g1 = w00 * Lc1[o00] + w01 * Lc1[o01] + w10 * Lc1[o10] + w11 * Lc1[o11];
            a1 = fmaf(val, g1, a1);
        }
    }
}

// 16 lanes per pixel. Lane l: cell l (phase 1, single accumulator), taps
// {l+16m} (selection), classes {l, l+16 if l<3} (gather + softmax/BCE).
// Register-light by construction: no per-lane arrays except osim[4].
__global__ __launch_bounds__(256, 4) void pfst_main(
    const float* __restrict__ trg, const float* __restrict__ ema,
    const float* __restrict__ xe,  const float* __restrict__ mix,
    const float* __restrict__ cn,  float* __restrict__ acc)
{
    int tid = threadIdx.x;
    int l = tid & 15;                 // lane in group
    int lw = tid & 63;                // lane in wave
    int grpbase = lw & 48;            // group's base lane within wave
    int g = tid >> 4;                 // pixel slot in block (0..15)
    int p = blockIdx.x * 16 + g;      // < 32768
    int b = p >> 14; int rem = p & 16383;
    int h = rem >> 7; int w = rem & 127;

    float mval = mix[(b << 14) + rem];
    bool active = mval < 0.5f;        // (1 - mix) > 0.5

    // ---------- Phase 1: lane l computes dot(center, cell l) over 64 channels --
    const float* Xb = xe + b * (NCF * NHX * NHX);
    const float* CNb = cn + (b << 10);
    int by = (h - 6) >> 2, bx = (w - 6) >> 2;
    int coff = (h >> 2) * 32 + (w >> 2);

    int offl;
    {
        int a = l >> 2, d = l & 3;
        int cy = by + a; cy = cy < 0 ? 0 : (cy > 31 ? 31 : cy);
        int cx2 = bx + d; cx2 = cx2 < 0 ? 0 : (cx2 > 31 ? 31 : cx2);
        offl = cy * 32 + cx2;
    }

    float dotl = 0.f;
    {
        const float* Xc = Xb;
        #pragma unroll 8
        for (int c = 0; c < NCF; c++) {
            dotl = fmaf(Xc[offl], Xc[coff], dotl);   // center load broadcasts
            Xc += NHX * NHX;
        }
    }
    float scell_l;
    {
        float nu = fmaxf(sqrtf(CNb[offl]), EPSC);
        float nc = fmaxf(sqrtf(CNb[coff]), EPSC);
        scell_l = dotl / (nu * nc);
    }

    // ---------- Phase 2: this lane's sims (taps k = l+16m) via shfl ----------
    bool ry = (h & 3) >= 2, rx = (w & 3) >= 2;
    float osim[4];
    unsigned unavail = 0u;
    #pragma unroll
    for (int m = 0; m < 4; m++) {
        int k = l + 16 * m;
        int i = (k * 586) >> 12; int j = k - 7 * i;
        int py = h + 2 * i - 6, px = w + 2 * j - 6;
        bool valid = (k < 49) && (unsigned)py < 128u && (unsigned)px < 128u;
        int a = (ry ? (i >> 1) : ((i + 1) >> 1)) & 3;   // QA/QB; clamped for k>=49
        int d = (rx ? (j >> 1) : ((j + 1) >> 1)) & 3;
        float v = __shfl(scell_l, grpbase + a * 4 + d); // unconditional: all lanes
        osim[m] = valid ? v : 0.f;
        if (k >= 49) unavail |= 1u << m;
    }

    // ---------- Phase 3+4: distributed top-9 / bottom-8 + gather ----------
    const float* Lb = ema + b * NC * NHE * NHE;
    bool two = (l < 3);
    const float* Lc0 = Lb + l * (NHE * NHE);
    const float* Lc1 = Lb + (l + 16) * (NHE * NHE);   // only read when two
    float ap0 = 0.f, ap1 = 0.f, an0 = 0.f, an1 = 0.f;

    // Pos: top-9 by value, ties -> lowest tap index (matches lax.top_k).
    {
        unsigned mask = unavail;
        #pragma unroll 1
        for (int t = 0; t < 9; t++) {
            float v = -3.4e38f; int idx = 63;
            #pragma unroll
            for (int m = 0; m < 4; m++) {
                if (!((mask >> m) & 1u) && osim[m] > v) { v = osim[m]; idx = l + 16 * m; }
            }
            #pragma unroll
            for (int s = 1; s < 16; s <<= 1) {
                float ov = __shfl_xor(v, s); int oi = __shfl_xor(idx, s);
                if (ov > v || (ov == v && oi < idx)) { v = ov; idx = oi; }
            }
            if ((idx & 15) == l) mask |= 1u << (idx >> 4);
            gather2(Lc0, Lc1, two, idx, v, h, w, ap0, ap1);
        }
    }
    // Neg: 8 smallest, ties -> lowest tap index (== top_k(-sim, 8)).
    {
        unsigned mask = unavail;
        #pragma unroll 1
        for (int t = 0; t < 8; t++) {
            float v = 3.4e38f; int idx = 63;
            #pragma unroll
            for (int m = 0; m < 4; m++) {
                if (!((mask >> m) & 1u) && osim[m] < v) { v = osim[m]; idx = l + 16 * m; }
            }
            #pragma unroll
            for (int s = 1; s < 16; s <<= 1) {
                float ov = __shfl_xor(v, s); int oi = __shfl_xor(idx, s);
                if (ov < v || (ov == v && oi < idx)) { v = ov; idx = oi; }
            }
            if ((idx & 15) == l) mask |= 1u << (idx >> 4);
            gather2(Lc0, Lc1, two, idx, v, h, w, an0, an1);
        }
    }

    // ---------- Phase 5: softmax + BCE, classes {l, l+16} ----------
    const float* Tb = trg + b * NC * (NH * NW) + (h << 7) + w;
    float x0 = Tb[l * (NH * NW)];
    float x1 = two ? Tb[(l + 16) * (NH * NW)] : 0.f;

    float mp = two ? fmaxf(ap0, ap1) : ap0;
    float mn = two ? fmaxf(an0, an1) : an0;
    #pragma unroll
    for (int s = 1; s < 16; s <<= 1) {
        mp = fmaxf(mp, __shfl_xor(mp, s));
        mn = fmaxf(mn, __shfl_xor(mn, s));
    }

    float ep = expf(ap0 - mp), en = expf(an0 - mn);
    float Zp = ep, Sp = ep * x0, Zn = en, Sn = en * x0;
    float ls = fminf(x0, 0.f) - log1pf(expf(-fabsf(x0)));
    float Bs = x0 - ls;
    if (two) {
        float ep1 = expf(ap1 - mp), en1 = expf(an1 - mn);
        Zp += ep1; Sp += ep1 * x1; Zn += en1; Sn += en1 * x1;
        float ls1 = fminf(x1, 0.f) - log1pf(expf(-fabsf(x1)));
        Bs += x1 - ls1;
    }
    #pragma unroll
    for (int s = 1; s < 16; s <<= 1) {
        Zp += __shfl_xor(Zp, s); Sp += __shfl_xor(Sp, s);
        Zn += __shfl_xor(Zn, s); Sn += __shfl_xor(Sn, s);
        Bs += __shfl_xor(Bs, s);
    }

    float lp = Bs - Sp / Zp;          // sum_c bce(x, pl_pos)
    float ln = Sn / Zn - Bs;          // sum_c -bce(x, pl_neg)
    if (!active || l != 0) { lp = 0.f; ln = 0.f; }
    float cm = (active && l == 0) ? 1.f : 0.f;

    // ---------- Wave reduce, block reduce, atomics ----------
    #pragma unroll
    for (int off = 32; off > 0; off >>= 1) {
        lp += __shfl_down(lp, off);
        ln += __shfl_down(ln, off);
        cm += __shfl_down(cm, off);
    }
    __shared__ float red[4][3];
    int wid = tid >> 6;
    if ((tid & 63) == 0) { red[wid][0] = lp; red[wid][1] = ln; red[wid][2] = cm; }
    __syncthreads();
    if (tid == 0) {
        atomicAdd(acc + 0, red[0][0] + red[1][0] + red[2][0] + red[3][0]);
        atomicAdd(acc + 1, red[0][1] + red[1][1] + red[2][1] + red[3][1]);
        atomicAdd(acc + 2, red[0][2] + red[1][2] + red[2][2] + red[3][2]);
    }
}

// Output: FLOAT32[2] = [loss_pos, 0.1*loss_neg] (decoded R0-R10, verified R11/R12).
__global__ void pfst_final(const float* __restrict__ acc, float* __restrict__ out) {
    float denom = acc[2] * (float)NC;
    out[0] = acc[0] / denom;              // loss_pos * W_POS(=1.0)
    out[1] = acc[1] / denom * 0.1f;       // loss_neg * W_NEG(=0.1)
}

extern "C" void kernel_launch(void* const* d_in, const int* in_sizes, int n_in,
                              void* d_out, int out_size, void* d_ws, size_t ws_size,
                              hipStream_t stream) {
    const float* trg = (const float*)d_in[0];   // [2,19,128,128]
    const float* ema = (const float*)d_in[1];   // [2,19,64,64]
    const float* xe  = (const float*)d_in[2];   // [2,64,32,32]
    const float* mix = (const float*)d_in[3];   // [2,1,128,128]
    float* acc = (float*)d_ws;
    float* cnw = (float*)((char*)d_ws + 64);    // 2048 floats
    float* out = (float*)d_out;

    hipLaunchKernelGGL(pfst_init, dim3(1), dim3(1), 0, stream, acc);
    hipLaunchKernelGGL(pfst_norm, dim3(8), dim3(256), 0, stream, xe, cnw);
    // 16 lanes/pixel: 16 pixels per 256-thread block -> 2048 blocks, 8192 waves.
    hipLaunchKernelGGL(pfst_main, dim3((NB * NH * NW) / 16), dim3(256), 0, stream,
                       trg, ema, xe, mix, cnw, acc);
    hipLaunchKernelGGL(pfst_final, dim3(1), dim3(1), 0, stream, acc, out);
}

// Round 15
// 74.409 us; speedup vs baseline: 2.5340x; 1.9455x over previous
//
#include <hip/hip_runtime.h>
#include <math.h>

// Problem constants
#define NB 2
#define NC 19      // classes
#define NH 128
#define NW 128
#define NCF 64     // feature channels
#define NHE 64     // ema logits H/W
#define NHX 32     // x_ema H/W
#define EPSC 1e-8f

// d_ws layout: acc[0..2] (64B pad) | cn[2048] f32 (8KB) | UP[622592] f32 (2.5MB)
#define WS_CN_OFF   64
#define WS_UP_OFF   (64 + 2048 * 4)
#define WS_UP_BYTES (NB * NC * NH * NW * 4)

__global__ void pfst_init(float* __restrict__ acc) {
    acc[0] = 0.f; acc[1] = 0.f; acc[2] = 0.f;
}

// Cell norms: cn[b*1024+pos] = sum_c xe[b,c,pos]^2
__global__ __launch_bounds__(256) void pfst_norm(const float* __restrict__ xe,
                                                 float* __restrict__ cn) {
    int idx = blockIdx.x * 256 + threadIdx.x;    // < 2048
    int b = idx >> 10, pos = idx & 1023;
    const float* X = xe + b * (NCF * 1024) + pos;
    float s = 0.f;
    #pragma unroll
    for (int c = 0; c < NCF; c++) { float v = X[c * 1024]; s = fmaf(v, v, s); }
    cn[idx] = s;
}

// Bilinear upsample ema 64x64 -> 128x128 (half-pixel, clamped) for all b,c.
__global__ __launch_bounds__(256) void pfst_upsample(const float* __restrict__ ema,
                                                     float* __restrict__ UP) {
    int idx = blockIdx.x * 256 + threadIdx.x;    // < 622592
    int px = idx & 127, py = (idx >> 7) & 127;
    int bc = idx >> 14;                          // 0..37
    const float* L = ema + bc * (NHE * NHE);
    int iy0 = (py - 1) >> 1; float ty = (py & 1) ? 0.25f : 0.75f;
    int ix0 = (px - 1) >> 1; float tx = (px & 1) ? 0.25f : 0.75f;
    int y0 = iy0 < 0 ? 0 : iy0;
    int y1 = (iy0 + 1) > 63 ? 63 : (iy0 + 1);
    int x0 = ix0 < 0 ? 0 : ix0;
    int x1 = (ix0 + 1) > 63 ? 63 : (ix0 + 1);
    float w00 = (1.f - ty) * (1.f - tx), w01 = (1.f - ty) * tx;
    float w10 = ty * (1.f - tx),         w11 = ty * tx;
    UP[idx] = w00 * L[y0 * 64 + x0] + w01 * L[y0 * 64 + x1]
            + w10 * L[y1 * 64 + x0] + w11 * L[y1 * 64 + x1];
}

// Fallback gather (no UP): accumulate val * bilinear(ema)[tap] into this
// lane's 5 classes {l, l+4, ...}.
__device__ __forceinline__ void gather_quad(const float* __restrict__ Lb,
                                            int py, int px, float val,
                                            int l, float (&accv)[5]) {
    int iy0 = (py - 1) >> 1; float ty = (py & 1) ? 0.25f : 0.75f;
    int ix0 = (px - 1) >> 1; float tx = (px & 1) ? 0.25f : 0.75f;
    int y0 = iy0 < 0 ? 0 : iy0;
    int y1 = (iy0 + 1) > 63 ? 63 : (iy0 + 1);
    int x0 = ix0 < 0 ? 0 : ix0;
    int x1 = (ix0 + 1) > 63 ? 63 : (ix0 + 1);
    float w00 = (1.f - ty) * (1.f - tx), w01 = (1.f - ty) * tx;
    float w10 = ty * (1.f - tx),         w11 = ty * tx;
    int o00 = y0 * 64 + x0, o01 = y0 * 64 + x1;
    int o10 = y1 * 64 + x0, o11 = y1 * 64 + x1;
    #pragma unroll
    for (int jc = 0; jc < 5; jc++) {
        int c = l + 4 * jc;
        if (c < NC) {
            const float* Lc = Lb + c * (NHE * NHE);
            float g = w00 * Lc[o00] + w01 * Lc[o01] + w10 * Lc[o10] + w11 * Lc[o11];
            accv[jc] = fmaf(val, g, accv[jc]);
        }
    }
}

// 4 lanes/pixel (R12 skeleton). Lane l: 16 feature channels (phase 1, dot
// only — norms hoisted to cn), redundant register-resident selection
// (proven tie semantics), classes {l,l+4,...} for gather + softmax/BCE.
__global__ __launch_bounds__(256) void pfst_main(
    const float* __restrict__ trg, const float* __restrict__ ema,
    const float* __restrict__ xe,  const float* __restrict__ mix,
    const float* __restrict__ cn,  const float* __restrict__ UP, int useUP,
    float* __restrict__ acc)
{
    int tid = threadIdx.x;
    int l = tid & 3;                      // lane in quad
    int q = tid >> 2;                     // pixel slot in block (0..63)
    int p = blockIdx.x * 64 + q;          // < 32768
    int b = p >> 14; int rem = p & 16383;
    int h = rem >> 7; int w = rem & 127;

    float mval = mix[(b << 14) + rem];
    bool active = mval < 0.5f;            // (1 - mix) > 0.5
    float lp = 0.f, ln = 0.f;
    float cm = (active && l == 0) ? 1.f : 0.f;

    if (active) {
        // ---------- Phase 1: cell dot products, 16 channels/lane ----------
        const float* Xb = xe + b * (NCF * NHX * NHX);
        const float* CNb = cn + (b << 10);
        int by = (h - 6) >> 2, bx = (w - 6) >> 2;
        int coff = (h >> 2) * 32 + (w >> 2);

        int offs[16];
        #pragma unroll
        for (int a = 0; a < 4; a++) {
            int cy = by + a; cy = cy < 0 ? 0 : (cy > 31 ? 31 : cy);
            #pragma unroll
            for (int d = 0; d < 4; d++) {
                int cx2 = bx + d; cx2 = cx2 < 0 ? 0 : (cx2 > 31 ? 31 : cx2);
                offs[a * 4 + d] = cy * 32 + cx2;
            }
        }

        float dotc[16];
        #pragma unroll
        for (int e = 0; e < 16; e++) dotc[e] = 0.f;

        const float* Xl = Xb + (l << 4) * (NHX * NHX);   // lane's 16 channels
        for (int cc = 0; cc < 16; cc++) {
            const float* Xc = Xl + cc * (NHX * NHX);
            float cv = Xc[coff];
            #pragma unroll
            for (int e = 0; e < 16; e++) dotc[e] = fmaf(Xc[offs[e]], cv, dotc[e]);
        }
        // quad allreduce of the 16 dots
        #pragma unroll
        for (int e = 0; e < 16; e++) {
            dotc[e] += __shfl_xor(dotc[e], 1); dotc[e] += __shfl_xor(dotc[e], 2);
        }

        float nc2 = 1.f / fmaxf(sqrtf(CNb[coff]), EPSC);
        float scell[16];
        #pragma unroll
        for (int e = 0; e < 16; e++) {
            float nu = fmaxf(sqrtf(CNb[offs[e]]), EPSC);
            scell[e] = dotc[e] * nc2 / nu;
        }

        // ---------- Phase 2: expand to 49 sims ----------
        const int QA[7] = {0, 0, 1, 1, 2, 2, 3};
        const int QB[7] = {0, 1, 1, 2, 2, 3, 3};
        bool ry = (h & 3) >= 2, rx = (w & 3) >= 2;

        float sims[49];
        #pragma unroll
        for (int i = 0; i < 7; i++) {
            int py = h + 2 * i - 6;
            bool vy = (unsigned)py < 128u;
            float srow[4];
            #pragma unroll
            for (int d = 0; d < 4; d++)
                srow[d] = ry ? scell[QA[i] * 4 + d] : scell[QB[i] * 4 + d];
            #pragma unroll
            for (int j = 0; j < 7; j++) {
                int px = w + 2 * j - 6;
                bool vx = (unsigned)px < 128u;
                float v = rx ? srow[QA[j]] : srow[QB[j]];
                sims[i * 7 + j] = (vy && vx) ? v : 0.f;
            }
        }

        // ---------- Phase 3: unfused selection -> register arrays ----------
        float vpos[9]; int ipos[9];
        {
            unsigned lo = 0u, hi = 0u;
            #pragma unroll
            for (int t = 0; t < 9; t++) {
                float best = -3.4e38f; int bi = 0;
                #pragma unroll
                for (int k = 0; k < 49; k++) {
                    bool freek = (k < 32) ? !((lo >> k) & 1u) : !((hi >> (k - 32)) & 1u);
                    if (freek && sims[k] > best) { best = sims[k]; bi = k; }
                }
                vpos[t] = best; ipos[t] = bi;
                if (bi < 32) lo |= 1u << bi; else hi |= 1u << (bi - 32);
            }
        }
        float vneg[8]; int ineg[8];
        {
            unsigned lo = 0u, hi = 0u;
            #pragma unroll
            for (int t = 0; t < 8; t++) {
                float best = 3.4e38f; int bi = 0;
                #pragma unroll
                for (int k = 0; k < 49; k++) {
                    bool freek = (k < 32) ? !((lo >> k) & 1u) : !((hi >> (k - 32)) & 1u);
                    if (freek && sims[k] < best) { best = sims[k]; bi = k; }
                }
                vneg[t] = best; ineg[t] = bi;
                if (bi < 32) lo |= 1u << bi; else hi |= 1u << (bi - 32);
            }
        }

        // ---------- Phase 4: gather (independent loads; UP fast path) ----------
        const float* Lb  = ema + b * NC * NHE * NHE;
        const float* UPb = UP + ((b * NC) << 14);
        float ap[5], an[5];
        #pragma unroll
        for (int jc = 0; jc < 5; jc++) { ap[jc] = 0.f; an[jc] = 0.f; }

        if (useUP) {
            #pragma unroll
            for (int t = 0; t < 9; t++) {
                int k = ipos[t];
                int i = (k * 586) >> 12; int j = k - 7 * i;
                int py = h + 2 * i - 6, px = w + 2 * j - 6;
                if ((unsigned)py < 128u && (unsigned)px < 128u) {
                    const float* U = UPb + (py << 7) + px;
                    float v = vpos[t];
                    #pragma unroll
                    for (int jc = 0; jc < 5; jc++) {
                        int c = l + 4 * jc;
                        if (c < NC) ap[jc] = fmaf(v, U[c << 14], ap[jc]);
                    }
                }
            }
            #pragma unroll
            for (int t = 0; t < 8; t++) {
                int k = ineg[t];
                int i = (k * 586) >> 12; int j = k - 7 * i;
                int py = h + 2 * i - 6, px = w + 2 * j - 6;
                if ((unsigned)py < 128u && (unsigned)px < 128u) {
                    const float* U = UPb + (py << 7) + px;
                    float v = vneg[t];
                    #pragma unroll
                    for (int jc = 0; jc < 5; jc++) {
                        int c = l + 4 * jc;
                        if (c < NC) an[jc] = fmaf(v, U[c << 14], an[jc]);
                    }
                }
            }
        } else {
            #pragma unroll
            for (int t = 0; t < 9; t++) {
                int k = ipos[t];
                int i = (k * 586) >> 12; int j = k - 7 * i;
                int py = h + 2 * i - 6, px = w + 2 * j - 6;
                if ((unsigned)py < 128u && (unsigned)px < 128u)
                    gather_quad(Lb, py, px, vpos[t], l, ap);
            }
            #pragma unroll
            for (int t = 0; t < 8; t++) {
                int k = ineg[t];
                int i = (k * 586) >> 12; int j = k - 7 * i;
                int py = h + 2 * i - 6, px = w + 2 * j - 6;
                if ((unsigned)py < 128u && (unsigned)px < 128u)
                    gather_quad(Lb, py, px, vneg[t], l, an);
            }
        }

        // ---------- Phase 5: softmax + BCE, classes split across quad ----------
        float mp = -3.4e38f, mn = -3.4e38f;
        #pragma unroll
        for (int jc = 0; jc < 5; jc++) {
            int c = l + 4 * jc;
            if (c < NC) { mp = fmaxf(mp, ap[jc]); mn = fmaxf(mn, an[jc]); }
        }
        mp = fmaxf(mp, __shfl_xor(mp, 1)); mp = fmaxf(mp, __shfl_xor(mp, 2));
        mn = fmaxf(mn, __shfl_xor(mn, 1)); mn = fmaxf(mn, __shfl_xor(mn, 2));

        float Zp = 0.f, Sp = 0.f, Zn = 0.f, Sn = 0.f, Bs = 0.f;
        const float* Tb = trg + b * NC * (NH * NW) + (h << 7) + w;
        #pragma unroll
        for (int jc = 0; jc < 5; jc++) {
            int c = l + 4 * jc;
            if (c < NC) {
                float x = Tb[c * (NH * NW)];
                float ep = expf(ap[jc] - mp); Zp += ep; Sp += ep * x;
                float en = expf(an[jc] - mn); Zn += en; Sn += en * x;
                float ls = fminf(x, 0.f) - log1pf(expf(-fabsf(x)));  // log_sigmoid
                Bs += x - ls;
            }
        }
        #pragma unroll
        for (int s = 1; s <= 2; s <<= 1) {
            Zp += __shfl_xor(Zp, s); Sp += __shfl_xor(Sp, s);
            Zn += __shfl_xor(Zn, s); Sn += __shfl_xor(Sn, s);
            Bs += __shfl_xor(Bs, s);
        }
        lp = Bs - Sp / Zp;        // sum_c bce(x, pl_pos)
        ln = Sn / Zn - Bs;        // sum_c -bce(x, pl_neg)
        if (l != 0) { lp = 0.f; ln = 0.f; }   // one contribution per pixel
    }

    // ---------- Wave reduce, block reduce, atomics ----------
    #pragma unroll
    for (int off = 32; off > 0; off >>= 1) {
        lp += __shfl_down(lp, off);
        ln += __shfl_down(ln, off);
        cm += __shfl_down(cm, off);
    }
    __shared__ float red[4][3];
    int wid = tid >> 6;
    if ((tid & 63) == 0) { red[wid][0] = lp; red[wid][1] = ln; red[wid][2] = cm; }
    __syncthreads();
    if (tid == 0) {
        atomicAdd(acc + 0, red[0][0] + red[1][0] + red[2][0] + red[3][0]);
        atomicAdd(acc + 1, red[0][1] + red[1][1] + red[2][1] + red[3][1]);
        atomicAdd(acc + 2, red[0][2] + red[1][2] + red[2][2] + red[3][2]);
    }
}

// Output: FLOAT32[2] = [loss_pos, 0.1*loss_neg] (decoded R0-R10, verified R11+).
__global__ void pfst_final(const float* __restrict__ acc, float* __restrict__ out) {
    float denom = acc[2] * (float)NC;
    out[0] = acc[0] / denom;              // loss_pos * W_POS(=1.0)
    out[1] = acc[1] / denom * 0.1f;       // loss_neg * W_NEG(=0.1)
}

extern "C" void kernel_launch(void* const* d_in, const int* in_sizes, int n_in,
                              void* d_out, int out_size, void* d_ws, size_t ws_size,
                              hipStream_t stream) {
    const float* trg = (const float*)d_in[0];   // [2,19,128,128]
    const float* ema = (const float*)d_in[1];   // [2,19,64,64]
    const float* xe  = (const float*)d_in[2];   // [2,64,32,32]
    const float* mix = (const float*)d_in[3];   // [2,1,128,128]
    float* acc = (float*)d_ws;
    float* cnw = (float*)((char*)d_ws + WS_CN_OFF);
    float* UP  = (float*)((char*)d_ws + WS_UP_OFF);
    int useUP = (ws_size >= (size_t)WS_UP_OFF + WS_UP_BYTES) ? 1 : 0;
    float* out = (float*)d_out;

    hipLaunchKernelGGL(pfst_init, dim3(1), dim3(1), 0, stream, acc);
    hipLaunchKernelGGL(pfst_norm, dim3(8), dim3(256), 0, stream, xe, cnw);
    if (useUP)
        hipLaunchKernelGGL(pfst_upsample, dim3((NB * NC * NH * NW) / 256), dim3(256),
                           0, stream, ema, UP);
    hipLaunchKernelGGL(pfst_main, dim3((NB * NH * NW) / 64), dim3(256), 0, stream,
                       trg, ema, xe, mix, cnw, UP, useUP, acc);
    hipLaunchKernelGGL(pfst_final, dim3(1), dim3(1), 0, stream, acc, out);
}

// Round 16
// 62.998 us; speedup vs baseline: 2.9930x; 1.1811x over previous
//
#include <hip/hip_runtime.h>
#include <math.h>

// Problem constants
#define NB 2
#define NC 19      // classes
#define NH 128
#define NW 128
#define NCF 64     // feature channels
#define NHE 64     // ema logits H/W
#define NHX 32     // x_ema H/W
#define EPSC 1e-8f

// d_ws: acc[0..2] (64B pad) | cn[2048] f32
#define WS_CN_OFF 64

__global__ void pfst_init(float* __restrict__ acc) {
    acc[0] = 0.f; acc[1] = 0.f; acc[2] = 0.f;
}

// Cell norms: cn[b*1024+pos] = sum_c xe[b,c,pos]^2
__global__ __launch_bounds__(256) void pfst_norm(const float* __restrict__ xe,
                                                 float* __restrict__ cn) {
    int idx = blockIdx.x * 256 + threadIdx.x;    // < 2048
    int b = idx >> 10, pos = idx & 1023;
    const float* X = xe + b * (NCF * 1024) + pos;
    float s = 0.f;
    #pragma unroll
    for (int c = 0; c < NCF; c++) { float v = X[c * 1024]; s = fmaf(v, v, s); }
    cn[idx] = s;
}

__device__ __forceinline__ int clampi(int v, int lo, int hi) {
    return v < lo ? lo : (v > hi ? hi : v);
}

// 4 lanes/pixel (R12 skeleton) + LDS staging of the block-shared ema/xe/cn
// tiles. Block = 64 consecutive-w pixels (same b,h). Read-only inputs stay
// the source of truth (no big intermediates -> no cross-XCD misses, R15 lesson).
__global__ __launch_bounds__(256) void pfst_main(
    const float* __restrict__ trg, const float* __restrict__ ema,
    const float* __restrict__ xe,  const float* __restrict__ mix,
    const float* __restrict__ cn,  float* __restrict__ acc)
{
    __shared__ float se[NC * 321];        // ema tile [19][8][40], stride 321 (pad)
    __shared__ float sx[NCF * 85];        // xe tile [64][4][21], stride 85 (pad)
    __shared__ float scn[84];             // cn tile [4][21]
    __shared__ float red[4][3];

    int tid = threadIdx.x;
    int l = tid & 3;                      // lane in quad
    int q = tid >> 2;                     // pixel slot (0..63)
    int p0 = blockIdx.x * 64;
    int b = p0 >> 14;
    int h = (p0 >> 7) & 127;              // block-uniform
    int w0 = p0 & 127;                    // 0 or 64
    int w = w0 + q;

    int ey0 = (h - 7) >> 1, ex0 = (w0 - 7) >> 1;   // ema tile origin
    int by0 = (h - 6) >> 2, bx0 = (w0 - 6) >> 2;   // cell tile origin

    // ---------- Stage tiles (all threads, before any divergence) ----------
    {
        const float* Eb = ema + b * NC * (NHE * NHE);
        for (int idx = tid; idx < NC * 8 * 40; idx += 256) {
            int c = idx / 320; int rr = idx - c * 320;
            int r = rr / 40;   int x = rr - r * 40;
            int gy = clampi(ey0 + r, 0, 63), gx = clampi(ex0 + x, 0, 63);
            se[c * 321 + rr] = Eb[c * (NHE * NHE) + gy * 64 + gx];
        }
        const float* Xb = xe + b * (NCF * NHX * NHX);
        for (int idx = tid; idx < NCF * 84; idx += 256) {
            int ch = idx / 84; int rr = idx - ch * 84;
            int a = rr / 21;   int d = rr - a * 21;
            int gy = clampi(by0 + a, 0, 31), gx = clampi(bx0 + d, 0, 31);
            sx[ch * 85 + rr] = Xb[ch * (NHX * NHX) + gy * 32 + gx];
        }
        const float* CNb = cn + (b << 10);
        if (tid < 84) {
            int a = tid / 21, d = tid - a * 21;
            int gy = clampi(by0 + a, 0, 31), gx = clampi(bx0 + d, 0, 31);
            scn[tid] = CNb[gy * 32 + gx];
        }
    }
    __syncthreads();

    float mval = mix[(b << 14) + (h << 7) + w];
    bool active = mval < 0.5f;            // (1 - mix) > 0.5
    float lp = 0.f, ln = 0.f;
    float cm = (active && l == 0) ? 1.f : 0.f;

    if (active) {
        // ---------- Phase 1: cell dots from LDS, 16 channels/lane ----------
        int bx = (w - 6) >> 2;
        int trow[4], tcol[4];
        #pragma unroll
        for (int a = 0; a < 4; a++) trow[a] = clampi(by0 + a, 0, 31) - by0;
        #pragma unroll
        for (int d = 0; d < 4; d++) tcol[d] = clampi(bx + d, 0, 31) - bx0;
        int cro = (h >> 2) - by0, cco = (w >> 2) - bx0;   // center tile coords
        int coffT = cro * 21 + cco;

        float dotc[16];
        #pragma unroll
        for (int e = 0; e < 16; e++) dotc[e] = 0.f;

        #pragma unroll 4
        for (int cc = 0; cc < 16; cc++) {
            const float* Sx = sx + (l * 16 + cc) * 85;
            float cv = Sx[coffT];
            #pragma unroll
            for (int a = 0; a < 4; a++) {
                int rb = trow[a] * 21;
                #pragma unroll
                for (int d = 0; d < 4; d++)
                    dotc[a * 4 + d] = fmaf(Sx[rb + tcol[d]], cv, dotc[a * 4 + d]);
            }
        }
        #pragma unroll
        for (int e = 0; e < 16; e++) {
            dotc[e] += __shfl_xor(dotc[e], 1); dotc[e] += __shfl_xor(dotc[e], 2);
        }

        float nc2 = 1.f / fmaxf(sqrtf(scn[coffT]), EPSC);
        float scell[16];
        #pragma unroll
        for (int a = 0; a < 4; a++) {
            #pragma unroll
            for (int d = 0; d < 4; d++) {
                float nu = fmaxf(sqrtf(scn[trow[a] * 21 + tcol[d]]), EPSC);
                scell[a * 4 + d] = dotc[a * 4 + d] * nc2 / nu;
            }
        }

        // ---------- Phase 2: expand to 49 sims ----------
        const int QA[7] = {0, 0, 1, 1, 2, 2, 3};
        const int QB[7] = {0, 1, 1, 2, 2, 3, 3};
        bool ry = (h & 3) >= 2, rx = (w & 3) >= 2;

        float sims[49];
        #pragma unroll
        for (int i = 0; i < 7; i++) {
            int py = h + 2 * i - 6;
            bool vy = (unsigned)py < 128u;
            float srow[4];
            #pragma unroll
            for (int d = 0; d < 4; d++)
                srow[d] = ry ? scell[QA[i] * 4 + d] : scell[QB[i] * 4 + d];
            #pragma unroll
            for (int j = 0; j < 7; j++) {
                int px = w + 2 * j - 6;
                bool vx = (unsigned)px < 128u;
                float v = rx ? srow[QA[j]] : srow[QB[j]];
                sims[i * 7 + j] = (vy && vx) ? v : 0.f;
            }
        }

        // ---------- Phase 3: selection -> register arrays (proven semantics) --
        float vpos[9]; int ipos[9];
        {
            unsigned lo = 0u, hi = 0u;
            #pragma unroll
            for (int t = 0; t < 9; t++) {
                float best = -3.4e38f; int bi = 0;
                #pragma unroll
                for (int k = 0; k < 49; k++) {
                    bool freek = (k < 32) ? !((lo >> k) & 1u) : !((hi >> (k - 32)) & 1u);
                    if (freek && sims[k] > best) { best = sims[k]; bi = k; }
                }
                vpos[t] = best; ipos[t] = bi;
                if (bi < 32) lo |= 1u << bi; else hi |= 1u << (bi - 32);
            }
        }
        float vneg[8]; int ineg[8];
        {
            unsigned lo = 0u, hi = 0u;
            #pragma unroll
            for (int t = 0; t < 8; t++) {
                float best = 3.4e38f; int bi = 0;
                #pragma unroll
                for (int k = 0; k < 49; k++) {
                    bool freek = (k < 32) ? !((lo >> k) & 1u) : !((hi >> (k - 32)) & 1u);
                    if (freek && sims[k] < best) { best = sims[k]; bi = k; }
                }
                vneg[t] = best; ineg[t] = bi;
                if (bi < 32) lo |= 1u << bi; else hi |= 1u << (bi - 32);
            }
        }

        // ---------- Phase 4: gather from LDS ema tile (bilinear recompute) ----
        float ap[5], an[5];
        #pragma unroll
        for (int jc = 0; jc < 5; jc++) { ap[jc] = 0.f; an[jc] = 0.f; }

        #pragma unroll
        for (int t = 0; t < 17; t++) {
            int k   = (t < 9) ? ipos[t] : ineg[t - 9];
            float v = (t < 9) ? vpos[t] : vneg[t - 9];
            int i = (k * 586) >> 12; int j = k - 7 * i;
            int py = h + 2 * i - 6, px = w + 2 * j - 6;
            if ((unsigned)py < 128u && (unsigned)px < 128u) {
                int iy0 = (py - 1) >> 1; float ty = (py & 1) ? 0.25f : 0.75f;
                int ix0 = (px - 1) >> 1; float tx = (px & 1) ? 0.25f : 0.75f;
                int y0 = clampi(iy0, 0, 63), y1 = clampi(iy0 + 1, 0, 63);
                int x0 = clampi(ix0, 0, 63), x1 = clampi(ix0 + 1, 0, 63);
                float w00 = (1.f - ty) * (1.f - tx), w01 = (1.f - ty) * tx;
                float w10 = ty * (1.f - tx),         w11 = ty * tx;
                int o00 = (y0 - ey0) * 40 + (x0 - ex0), o01 = (y0 - ey0) * 40 + (x1 - ex0);
                int o10 = (y1 - ey0) * 40 + (x0 - ex0), o11 = (y1 - ey0) * 40 + (x1 - ex0);
                #pragma unroll
                for (int jc = 0; jc < 5; jc++) {
                    int c = l + 4 * jc;
                    if (c < NC) {
                        const float* Sc = se + c * 321;
                        float g = w00 * Sc[o00] + w01 * Sc[o01]
                                + w10 * Sc[o10] + w11 * Sc[o11];
                        if (t < 9) ap[jc] = fmaf(v, g, ap[jc]);
                        else       an[jc] = fmaf(v, g, an[jc]);
                    }
                }
            }
        }

        // ---------- Phase 5: softmax + BCE, classes split across quad ----------
        float mp = -3.4e38f, mn = -3.4e38f;
        #pragma unroll
        for (int jc = 0; jc < 5; jc++) {
            int c = l + 4 * jc;
            if (c < NC) { mp = fmaxf(mp, ap[jc]); mn = fmaxf(mn, an[jc]); }
        }
        mp = fmaxf(mp, __shfl_xor(mp, 1)); mp = fmaxf(mp, __shfl_xor(mp, 2));
        mn = fmaxf(mn, __shfl_xor(mn, 1)); mn = fmaxf(mn, __shfl_xor(mn, 2));

        float Zp = 0.f, Sp = 0.f, Zn = 0.f, Sn = 0.f, Bs = 0.f;
        const float* Tb = trg + b * NC * (NH * NW) + (h << 7) + w;
        #pragma unroll
        for (int jc = 0; jc < 5; jc++) {
            int c = l + 4 * jc;
            if (c < NC) {
                float x = Tb[c * (NH * NW)];
                float ep = expf(ap[jc] - mp); Zp += ep; Sp += ep * x;
                float en = expf(an[jc] - mn); Zn += en; Sn += en * x;
                float ls = fminf(x, 0.f) - log1pf(expf(-fabsf(x)));  // log_sigmoid
                Bs += x - ls;
            }
        }
        #pragma unroll
        for (int s = 1; s <= 2; s <<= 1) {
            Zp += __shfl_xor(Zp, s); Sp += __shfl_xor(Sp, s);
            Zn += __shfl_xor(Zn, s); Sn += __shfl_xor(Sn, s);
            Bs += __shfl_xor(Bs, s);
        }
        lp = Bs - Sp / Zp;        // sum_c bce(x, pl_pos)
        ln = Sn / Zn - Bs;        // sum_c -bce(x, pl_neg)
        if (l != 0) { lp = 0.f; ln = 0.f; }   // one contribution per pixel
    }

    // ---------- Wave reduce, block reduce, atomics ----------
    #pragma unroll
    for (int off = 32; off > 0; off >>= 1) {
        lp += __shfl_down(lp, off);
        ln += __shfl_down(ln, off);
        cm += __shfl_down(cm, off);
    }
    int wid = tid >> 6;
    if ((tid & 63) == 0) { red[wid][0] = lp; red[wid][1] = ln; red[wid][2] = cm; }
    __syncthreads();
    if (tid == 0) {
        atomicAdd(acc + 0, red[0][0] + red[1][0] + red[2][0] + red[3][0]);
        atomicAdd(acc + 1, red[0][1] + red[1][1] + red[2][1] + red[3][1]);
        atomicAdd(acc + 2, red[0][2] + red[1][2] + red[2][2] + red[3][2]);
    }
}

// Output: FLOAT32[2] = [loss_pos, 0.1*loss_neg] (decoded R0-R10, verified R11+).
__global__ void pfst_final(const float* __restrict__ acc, float* __restrict__ out) {
    float denom = acc[2] * (float)NC;
    out[0] = acc[0] / denom;              // loss_pos * W_POS(=1.0)
    out[1] = acc[1] / denom * 0.1f;       // loss_neg * W_NEG(=0.1)
}

extern "C" void kernel_launch(void* const* d_in, const int* in_sizes, int n_in,
                              void* d_out, int out_size, void* d_ws, size_t ws_size,
                              hipStream_t stream) {
    const float* trg = (const float*)d_in[0];   // [2,19,128,128]
    const float* ema = (const float*)d_in[1];   // [2,19,64,64]
    const float* xe  = (const float*)d_in[2];   // [2,64,32,32]
    const float* mix = (const float*)d_in[3];   // [2,1,128,128]
    float* acc = (float*)d_ws;
    float* cnw = (float*)((char*)d_ws + WS_CN_OFF);
    float* out = (float*)d_out;

    hipLaunchKernelGGL(pfst_init, dim3(1), dim3(1), 0, stream, acc);
    hipLaunchKernelGGL(pfst_norm, dim3(8), dim3(256), 0, stream, xe, cnw);
    hipLaunchKernelGGL(pfst_main, dim3((NB * NH * NW) / 64), dim3(256), 0, stream,
                       trg, ema, xe, mix, cnw, acc);
    hipLaunchKernelGGL(pfst_final, dim3(1), dim3(1), 0, stream, acc, out);
}